// Round 10
// baseline (424.312 us; speedup 1.0000x reference)
//
#include <hip/hip_runtime.h>
#include <math.h>

#define NN 20000
#define NE 320000

typedef _Float16 f16x8 __attribute__((ext_vector_type(8)));
typedef float f32x4 __attribute__((ext_vector_type(4)));
typedef unsigned short ushort_t;
typedef unsigned int uint_t;

#define MFMA16(A,B,C) __builtin_amdgcn_mfma_f32_16x16x32_f16((A),(B),(C),0,0,0)
#define LDS_FENCE() do{ asm volatile("s_waitcnt lgkmcnt(0)" ::: "memory"); __builtin_amdgcn_sched_barrier(0);}while(0)

static_assert(NE % 256 == 0, "edge grid must tile exactly");

__device__ __forceinline__ float frelu(float x){ return fmaxf(x, 0.0f); }

// split x = hi + lo * 2^-11  (lo stored pre-scaled by 2^11 to stay f16-normal)
__device__ __forceinline__ void splitf(float x, ushort_t& h, ushort_t& l){
    _Float16 hh = (_Float16)x;
    float r = (x - (float)hh) * 2048.0f;
    _Float16 ll = (_Float16)r;
    union { _Float16 f; ushort_t u; } ch, cl;
    ch.f = hh; cl.f = ll;
    h = ch.u; l = cl.u;
}

__device__ __forceinline__ void edge_embed(
    int e, int s, int d,
    const float* __restrict__ pos,
    const float* __restrict__ edge_bond,
    const float* __restrict__ em_w1, const float* __restrict__ em_b1,
    const float* __restrict__ em_w2, const float* __restrict__ em_b2,
    float* eemb, float* sh1)
{
    float vx = pos[d*3+0] - pos[s*3+0];
    float vy = pos[d*3+1] - pos[s*3+1];
    float vz = pos[d*3+2] - pos[s*3+2];
    float d2 = vx*vx + vy*vy + vz*vz + 1e-12f;
    float dist = sqrtf(d2);
    float inv = 1.0f / (dist + 1e-8f);
    const float SQ3 = 1.7320508075688772f;
    sh1[0] = SQ3 * vx * inv;
    sh1[1] = SQ3 * vy * inv;
    sh1[2] = SQ3 * vz * inv;

    float ein[42];
    #pragma unroll
    for (int t = 0; t < 10; ++t) ein[t] = edge_bond[e*10 + t];
    const float coeff = -19.22f;            // -0.5 / (5/31)^2
    const float step  = 5.0f / 31.0f;
    #pragma unroll
    for (int k = 0; k < 32; ++k) {
        float dd = dist - step * (float)k;
        ein[10+k] = __expf(coeff * dd * dd);
    }

    float t1[16];
    #pragma unroll
    for (int j = 0; j < 16; ++j) t1[j] = em_b1[j];
    #pragma unroll
    for (int t = 0; t < 42; ++t) {
        float v = ein[t];
        #pragma unroll
        for (int j = 0; j < 16; ++j) t1[j] += v * em_w1[t*16 + j];
    }
    #pragma unroll
    for (int j = 0; j < 16; ++j) t1[j] = frelu(t1[j]);

    #pragma unroll
    for (int j = 0; j < 16; ++j) eemb[j] = em_b2[j];
    #pragma unroll
    for (int t = 0; t < 16; ++t) {
        float v = t1[t];
        #pragma unroll
        for (int j = 0; j < 16; ++j) eemb[j] += v * em_w2[t*16 + j];
    }
}

// ---------- CSR construction ----------
__global__ __launch_bounds__(256)
void k_deg(const int* __restrict__ ei, int* __restrict__ deg)
{
    int e = blockIdx.x*256 + threadIdx.x;
    if (e < NE) atomicAdd(&deg[ei[e]], 1);
}

__global__ __launch_bounds__(256)
void k_scan(const int* __restrict__ deg, int* __restrict__ rowptr, int* __restrict__ off)
{
    __shared__ int part[256];
    int t = threadIdx.x;
    const int chunk = (NN + 255) / 256;       // 79
    int lo = t*chunk, hi = lo + chunk; if (hi > NN) hi = NN; if (lo > NN) lo = NN;
    int s = 0;
    for (int i = lo; i < hi; ++i) s += deg[i];
    part[t] = s;
    __syncthreads();
    for (int ofs = 1; ofs < 256; ofs <<= 1) {
        int v = (t >= ofs) ? part[t-ofs] : 0;
        __syncthreads();
        part[t] += v;
        __syncthreads();
    }
    int run = (t == 0) ? 0 : part[t-1];
    for (int i = lo; i < hi; ++i) {
        rowptr[i] = run; off[i] = run;
        run += deg[i];
    }
    if (t == 255) rowptr[NN] = NE;
}

__global__ __launch_bounds__(256)
void k_scatter(const int* __restrict__ ei, int* __restrict__ off, int* __restrict__ perm)
{
    int e = blockIdx.x*256 + threadIdx.x;
    if (e >= NE) return;
    int p = atomicAdd(&off[ei[e]], 1);
    perm[p] = e;
}

// ---- per-node W1 partials: yB = node@W1[16:32], yC = node@W1[32:48] ----
__global__ __launch_bounds__(256)
void k_node_y(const float* __restrict__ node, int stride,
              const float* __restrict__ w1, float* __restrict__ y)
{
    int n = blockIdx.x*256 + threadIdx.x;
    if (n >= NN) return;
    float sv[16];
    const float4* r = reinterpret_cast<const float4*>(node + (size_t)n*stride);
    #pragma unroll
    for (int k = 0; k < 4; ++k) {
        float4 q = r[k];
        sv[4*k]=q.x; sv[4*k+1]=q.y; sv[4*k+2]=q.z; sv[4*k+3]=q.w;
    }
    float yb[48];
    #pragma unroll
    for (int j = 0; j < 48; ++j) yb[j] = 0.f;
    #pragma unroll
    for (int t = 0; t < 16; ++t) {
        float v = sv[t];
        #pragma unroll
        for (int j = 0; j < 48; ++j) yb[j] += v * w1[(16+t)*48 + j];
    }
    float* yo = y + (size_t)n*96;
    #pragma unroll
    for (int j = 0; j < 12; ++j)
        reinterpret_cast<float4*>(yo)[j] = make_float4(yb[4*j], yb[4*j+1], yb[4*j+2], yb[4*j+3]);
    #pragma unroll
    for (int j = 0; j < 48; ++j) yb[j] = 0.f;
    #pragma unroll
    for (int t = 0; t < 16; ++t) {
        float v = sv[t];
        #pragma unroll
        for (int j = 0; j < 48; ++j) yb[j] += v * w1[(32+t)*48 + j];
    }
    #pragma unroll
    for (int j = 0; j < 12; ++j)
        reinterpret_cast<float4*>(yo + 48)[j] = make_float4(yb[4*j], yb[4*j+1], yb[4*j+2], yb[4*j+3]);
}

// One-time pack of W2' (K=49 rows incl bias, zero-pad to 64) into global hi/lo
__global__ __launch_bounds__(256)
void k_pack(const float* __restrict__ w2, const float* __restrict__ b2,
            ushort_t* __restrict__ out, int NC, int ntiles)
{
    int slot = blockIdx.x*256 + threadIdx.x;
    if (slot >= ntiles*128) return;
    int tl = slot >> 7; int r7 = slot & 127; int kb = r7 >> 6; int ll = r7 & 63;
    int col = tl*16 + (ll & 15);
    int k0 = (kb<<5) + ((ll>>4)<<3);
    uint_t hw[4], lw[4];
    #pragma unroll
    for (int p = 0; p < 4; ++p) {
        int ka = k0 + 2*p, kb2 = k0 + 2*p + 1;
        float va = (ka < 48) ? w2[ka*NC + col] : (ka == 48 ? b2[col] : 0.0f);
        float vb = (kb2 < 48) ? w2[kb2*NC + col] : (kb2 == 48 ? b2[col] : 0.0f);
        ushort_t ah, al, bh, bl;
        splitf(va, ah, al);
        splitf(vb, bh, bl);
        hw[p] = (uint_t)ah | ((uint_t)bh << 16);
        lw[p] = (uint_t)al | ((uint_t)bl << 16);
    }
    int base = tl*2048 + kb*1024 + ll*8;
    *reinterpret_cast<uint4*>(&out[base])       = make_uint4(hw[0], hw[1], hw[2], hw[3]);
    *reinterpret_cast<uint4*>(&out[base + 512]) = make_uint4(lw[0], lw[1], lw[2], lw[3]);
}

struct B4 { f16x8 h0, l0, h1, l1; };
__device__ __forceinline__ B4 loadB(const f16x8* __restrict__ g, int t, int l) {
    B4 b;
    const f16x8* p = g + t*256 + l;
    b.h0 = p[0];
    b.l0 = p[64];
    b.h1 = p[128];
    b.l1 = p[192];
    return b;
}

// Per-wave A-frag staging through a 4 KB bounce (hi+lo in one pass, 2 fences/mt).
__device__ __forceinline__ void stage_A(ushort_t* bounce, int l,
                                        const uint_t* hph, const uint_t* hpl,
                                        f16x8 ahi[4][2], f16x8 alo[4][2])
{
    #pragma unroll
    for (int t = 0; t < 4; ++t)
        *reinterpret_cast<uint4*>(&bounce[l*32 + t*8]) = make_uint4(0,0,0,0);
    LDS_FENCE();
    #pragma unroll
    for (int mt = 0; mt < 4; ++mt) {
        if ((l >> 4) == mt) {
            #pragma unroll
            for (int jj = 0; jj < 25; ++jj) {
                int k = jj*2, kb = k >> 5, kk = k & 31;
                int lr = (l & 15) + ((kk >> 3) << 4);
                int off = kb*512 + lr*8 + (kk & 7);
                *reinterpret_cast<uint_t*>(&bounce[off])        = hph[jj];
                *reinterpret_cast<uint_t*>(&bounce[1024 + off]) = hpl[jj];
            }
        }
        LDS_FENCE();
        ahi[mt][0] = *reinterpret_cast<const f16x8*>(&bounce[l*8]);
        ahi[mt][1] = *reinterpret_cast<const f16x8*>(&bounce[512 + l*8]);
        alo[mt][0] = *reinterpret_cast<const f16x8*>(&bounce[1024 + l*8]);
        alo[mt][1] = *reinterpret_cast<const f16x8*>(&bounce[1536 + l*8]);
        LDS_FENCE();
    }
}

// h = relu(b1 + em@W1[0:16] + yB[s] + yC[d]), em already in registers
__device__ __forceinline__ void build_h_reg(
    const float* em, int s, int d,
    const float* __restrict__ y,
    const float* __restrict__ w1, const float* __restrict__ b1,
    float* h)
{
    #pragma unroll
    for (int j = 0; j < 48; ++j) h[j] = b1[j];
    #pragma unroll
    for (int t = 0; t < 16; ++t) {
        float v = em[t];
        #pragma unroll
        for (int j = 0; j < 48; ++j) h[j] += v * w1[t*48 + j];
    }
    const float4* pb = reinterpret_cast<const float4*>(y + (size_t)s*96);
    const float4* pc = reinterpret_cast<const float4*>(y + (size_t)d*96 + 48);
    #pragma unroll
    for (int kk = 0; kk < 12; ++kk) {
        float4 qb = pb[kk], qc = pc[kk];
        h[4*kk+0] = frelu(h[4*kk+0] + qb.x + qc.x);
        h[4*kk+1] = frelu(h[4*kk+1] + qb.y + qc.y);
        h[4*kk+2] = frelu(h[4*kk+2] + qb.z + qc.z);
        h[4*kk+3] = frelu(h[4*kk+3] + qb.w + qc.w);
    }
}

__global__ __launch_bounds__(256)
void k_node_feat(const int* __restrict__ x_cat, const float* __restrict__ x_scalar,
                 const float* __restrict__ emb, const float* __restrict__ node_w,
                 const float* __restrict__ node_b, float* __restrict__ node0)
{
    int n = blockIdx.x * 256 + threadIdx.x;
    if (n >= NN) return;
    float acc[16];
    #pragma unroll
    for (int k = 0; k < 16; ++k) acc[k] = node_b[k];
    #pragma unroll
    for (int c = 0; c < 10; ++c) {
        int idx = x_cat[n*10 + c];
        const float4* row = reinterpret_cast<const float4*>(emb + (c*119 + idx)*16);
        #pragma unroll
        for (int k = 0; k < 4; ++k) {
            float4 q = row[k];
            acc[4*k+0] += q.x; acc[4*k+1] += q.y; acc[4*k+2] += q.z; acc[4*k+3] += q.w;
        }
    }
    #pragma unroll
    for (int t = 0; t < 32; ++t) {
        float xs = x_scalar[n*32 + t];
        #pragma unroll
        for (int k = 0; k < 16; ++k) acc[k] += xs * node_w[t*16 + k];
    }
    #pragma unroll
    for (int k = 0; k < 16; ++k) node0[n*16 + k] = acc[k];
}

// ---------------- Layer 1 (fused geometry+embed; stores tp rows, no atomics) ----------------
__global__ __launch_bounds__(256)
void k_edge_l1(const int* __restrict__ ei, const float* __restrict__ pos,
               const float* __restrict__ edge_bond,
               const float* __restrict__ em_w1, const float* __restrict__ em_b1,
               const float* __restrict__ em_w2, const float* __restrict__ em_b2,
               const float* __restrict__ w1, const float* __restrict__ b1,
               const ushort_t* __restrict__ packW,
               const float* __restrict__ y,
               const float* __restrict__ node0,
               const int* __restrict__ perm,
               float* __restrict__ eembG, float* __restrict__ eshG,
               float* __restrict__ tp)
{
    __shared__ __align__(16) unsigned char smem[20736];
    float* sT  = (float*)smem;                    // 16*260*4 = 16640
    float* sSh = (float*)(smem + 16640);          // 3072

    int tid = threadIdx.x;
    int l = tid & 63;
    int cc = l & 15;
    int i = blockIdx.x*256 + tid;
    int e = perm[i];
    int s = ei[e], d = ei[NE + e];
    size_t rowbase = (size_t)blockIdx.x * 256;

    float em[16], sh1[3];
    edge_embed(e, s, d, pos, edge_bond, em_w1, em_b1, em_w2, em_b2, em, sh1);
    // persist for layer 2 (indexed by sorted position i -> coalesced both ways)
    {
        float4* pe = reinterpret_cast<float4*>(eembG + (size_t)i*16);
        #pragma unroll
        for (int k = 0; k < 4; ++k)
            pe[k] = make_float4(em[4*k], em[4*k+1], em[4*k+2], em[4*k+3]);
        reinterpret_cast<float4*>(eshG)[i] = make_float4(sh1[0], sh1[1], sh1[2], 0.f);
    }

    float sd[16];
    {
        const float4* rd = reinterpret_cast<const float4*>(node0 + (size_t)d*16);
        #pragma unroll
        for (int k = 0; k < 4; ++k) {
            float4 q = rd[k];
            sd[4*k]=q.x; sd[4*k+1]=q.y; sd[4*k+2]=q.z; sd[4*k+3]=q.w;
        }
    }
    float h[48];
    build_h_reg(em, s, d, y, w1, b1, h);

    uint_t hph[25], hpl[25];
    #pragma unroll
    for (int jj = 0; jj < 24; ++jj) {
        ushort_t ah, al, bh, bl;
        splitf(h[2*jj],   ah, al);
        splitf(h[2*jj+1], bh, bl);
        hph[jj] = (uint_t)ah | ((uint_t)bh << 16);
        hpl[jj] = (uint_t)al | ((uint_t)bl << 16);
    }
    hph[24] = 0x3C00u;  // k=48 -> 1.0 (bias feature), k=49 -> 0
    hpl[24] = 0u;

    f16x8 ahi[4][2], alo[4][2];
    stage_A((ushort_t*)smem + (tid >> 6)*2048, l, hph, hpl, ahi, alo);

    __syncthreads();            // bounce dead; now fill the union region
    #pragma unroll
    for (int u = 0; u < 16; ++u) sT[u*260 + tid] = sd[u];
    sSh[tid*3+0] = sh1[0]; sSh[tid*3+1] = sh1[1]; sSh[tid*3+2] = sh1[2];
    __syncthreads();

    f32x4 out0[4];
    float ob[4][4];
    #pragma unroll
    for (int mt = 0; mt < 4; ++mt) {
        out0[mt] = (f32x4){0.f,0.f,0.f,0.f};
        #pragma unroll
        for (int r = 0; r < 4; ++r) ob[mt][r] = 0.f;
    }

    const f16x8* gB = reinterpret_cast<const f16x8*>(packW);

    auto process = [&](int t, const B4& cur) {
        #pragma unroll
        for (int mt = 0; mt < 4; ++mt) {
            f32x4 Dh = (f32x4){0.f,0.f,0.f,0.f};
            f32x4 Dc = (f32x4){0.f,0.f,0.f,0.f};
            Dh = MFMA16(ahi[mt][0], cur.h0, Dh);
            Dh = MFMA16(ahi[mt][1], cur.h1, Dh);
            Dc = MFMA16(alo[mt][0], cur.h0, Dc);
            Dc = MFMA16(ahi[mt][0], cur.l0, Dc);
            Dc = MFMA16(alo[mt][1], cur.h1, Dc);
            Dc = MFMA16(ahi[mt][1], cur.l1, Dc);
            f32x4 D = Dh + Dc * 0.00048828125f;   // 2^-11
            int elb = (tid & 192) + (mt << 4) + ((l >> 4) << 2);
            if (t < 16) {
                f32x4 sv = *reinterpret_cast<const f32x4*>(&sT[t*260 + elb]);
                out0[mt] += sv * D;
            } else {
                const float* sp = &sT[(((t-16)<<2) + (cc>>2))*260 + elb];
                #pragma unroll
                for (int r = 0; r < 4; ++r) ob[mt][r] += sp[r] * D[r];
            }
        }
    };

    B4 b0 = loadB(gB, 0, l), b1v = loadB(gB, 1, l);
    #pragma unroll 1
    for (int t = 0; t < 20; t += 2) {
        B4 p0 = (t + 2 < 20) ? loadB(gB, t + 2, l) : b0;
        process(t, b0);
        B4 p1 = (t + 3 < 20) ? loadB(gB, t + 3, l) : b1v;
        process(t + 1, b1v);
        b0 = p0; b1v = p1;
    }

    // epilogue: dense stores at row (blockbase + el)
    #pragma unroll
    for (int mt = 0; mt < 4; ++mt) {
        int elb = (tid & 192) + (mt << 4) + ((l >> 4) << 2);
        #pragma unroll
        for (int r = 0; r < 4; ++r) {
            int el = elb + r;
            float* row = tp + (rowbase + el)*28;
            row[cc] = out0[mt][r] * 0.25f;
            float x = ob[mt][r];
            x += __shfl_xor(x, 4); x += __shfl_xor(x, 8);
            int q = cc / 3; int i2 = cc - q*3;
            float xq = __shfl(x, (l & 48) | q);
            if (cc < 12)
                row[16 + cc] = 0.25f * xq * sSh[el*3 + i2];
        }
    }
}

// ---------------- Layer 2 (stores tp rows, no atomics) ----------------
__global__ __launch_bounds__(256)
void k_edge_l2(const int* __restrict__ ei,
               const float* __restrict__ w1, const float* __restrict__ b1,
               const ushort_t* __restrict__ packW,
               const float* __restrict__ eembG, const float* __restrict__ eshG,
               const float* __restrict__ y,
               const float* __restrict__ node1,
               const int* __restrict__ perm,
               float* __restrict__ tp)
{
    __shared__ __align__(16) unsigned char smem[36352];
    float* sT  = (float*)smem;                    // 16640
    float* sVd = (float*)(smem + 16640);          // 4160
    float* sV  = (float*)(smem + 20800);          // 12480
    float* sSh = (float*)(smem + 33280);          // 3072

    int tid = threadIdx.x;
    int l = tid & 63;
    int cc = l & 15;
    int i = blockIdx.x*256 + tid;
    int e = perm[i];
    int s = ei[e], d = ei[NE + e];
    size_t rowbase = (size_t)blockIdx.x * 256;

    float4 shv = reinterpret_cast<const float4*>(eshG)[i];
    float sh1[3] = {shv.x, shv.y, shv.z};
    float sd[16], vv[12];
    {
        const float4* rd = reinterpret_cast<const float4*>(node1 + (size_t)d*28);
        #pragma unroll
        for (int k = 0; k < 4; ++k) {
            float4 q = rd[k];
            sd[4*k]=q.x; sd[4*k+1]=q.y; sd[4*k+2]=q.z; sd[4*k+3]=q.w;
        }
        #pragma unroll
        for (int k = 0; k < 3; ++k) {
            float4 q = rd[4+k];
            vv[4*k]=q.x; vv[4*k+1]=q.y; vv[4*k+2]=q.z; vv[4*k+3]=q.w;
        }
    }
    float vdr[4];
    const float INV_SQ3 = 0.5773502691896258f;
    #pragma unroll
    for (int u = 0; u < 4; ++u)
        vdr[u] = (vv[u*3]*sh1[0] + vv[u*3+1]*sh1[1] + vv[u*3+2]*sh1[2]) * INV_SQ3;

    float em[16];
    {
        const float4* pe = reinterpret_cast<const float4*>(eembG + (size_t)i*16);
        #pragma unroll
        for (int k = 0; k < 4; ++k) {
            float4 q = pe[k];
            em[4*k]=q.x; em[4*k+1]=q.y; em[4*k+2]=q.z; em[4*k+3]=q.w;
        }
    }
    float h[48];
    build_h_reg(em, s, d, y, w1, b1, h);

    uint_t hph[25], hpl[25];
    #pragma unroll
    for (int jj = 0; jj < 24; ++jj) {
        ushort_t ah, al, bh, bl;
        splitf(h[2*jj],   ah, al);
        splitf(h[2*jj+1], bh, bl);
        hph[jj] = (uint_t)ah | ((uint_t)bh << 16);
        hpl[jj] = (uint_t)al | ((uint_t)bl << 16);
    }
    hph[24] = 0x3C00u;
    hpl[24] = 0u;

    f16x8 ahi[4][2], alo[4][2];
    stage_A((ushort_t*)smem + (tid >> 6)*2048, l, hph, hpl, ahi, alo);

    __syncthreads();
    #pragma unroll
    for (int u = 0; u < 16; ++u) sT[u*260 + tid] = sd[u];
    #pragma unroll
    for (int u = 0; u < 4; ++u) sVd[u*260 + tid] = vdr[u];
    #pragma unroll
    for (int k = 0; k < 12; ++k) sV[k*260 + tid] = vv[k];
    sSh[tid*3+0] = sh1[0]; sSh[tid*3+1] = sh1[1]; sSh[tid*3+2] = sh1[2];
    __syncthreads();

    const float A0 = 0.22360679774997896f;   // 1/sqrt(20)
    const float AE = 0.3535533905932738f;    // 0.5/sqrt(2)

    f32x4 out0[4];
    float outc[4][4];
    #pragma unroll
    for (int mt = 0; mt < 4; ++mt) {
        out0[mt] = (f32x4){0.f,0.f,0.f,0.f};
        #pragma unroll
        for (int r = 0; r < 4; ++r) outc[mt][r] = 0.f;
    }

    const f16x8* gB = reinterpret_cast<const f16x8*>(packW);

    auto process = [&](int t, const B4& cur) {
        #pragma unroll
        for (int mt = 0; mt < 4; ++mt) {
            f32x4 Dh = (f32x4){0.f,0.f,0.f,0.f};
            f32x4 Dc = (f32x4){0.f,0.f,0.f,0.f};
            Dh = MFMA16(ahi[mt][0], cur.h0, Dh);
            Dh = MFMA16(ahi[mt][1], cur.h1, Dh);
            Dc = MFMA16(alo[mt][0], cur.h0, Dc);
            Dc = MFMA16(ahi[mt][0], cur.l0, Dc);
            Dc = MFMA16(alo[mt][1], cur.h1, Dc);
            Dc = MFMA16(ahi[mt][1], cur.l1, Dc);
            f32x4 D = Dh + Dc * 0.00048828125f;
            int elb = (tid & 192) + (mt << 4) + ((l >> 4) << 2);
            if (t < 16) {                     // wa: contract s
                f32x4 sv = *reinterpret_cast<const f32x4*>(&sT[t*260 + elb]);
                out0[mt] += sv * D;
            } else if (t < 20) {              // wb: contract vdot/sqrt3
                f32x4 vd = *reinterpret_cast<const f32x4*>(&sVd[(t-16)*260 + elb]);
                out0[mt] += vd * D;
            } else if (t < 24) {              // wc: contract s -> outc[q]
                const float* sp = &sT[(((t-20)<<2) + (cc>>2))*260 + elb];
                #pragma unroll
                for (int r = 0; r < 4; ++r) outc[mt][r] += sp[r] * D[r];
            } else if (t == 24) {             // wd: store cols 16..27
                int base3 = (cc >> 2) * 3;
                #pragma unroll
                for (int r = 0; r < 4; ++r) {
                    int el = elb + r;
                    float vx = sV[(base3+0)*260 + el];
                    float vy = sV[(base3+1)*260 + el];
                    float vz = sV[(base3+2)*260 + el];
                    float a0 = D[r]*vx, a1 = D[r]*vy, a2 = D[r]*vz;
                    a0 += __shfl_xor(a0,4); a0 += __shfl_xor(a0,8);
                    a1 += __shfl_xor(a1,4); a1 += __shfl_xor(a1,8);
                    a2 += __shfl_xor(a2,4); a2 += __shfl_xor(a2,8);
                    float xc = outc[mt][r];
                    xc += __shfl_xor(xc,4); xc += __shfl_xor(xc,8);
                    int q = cc / 3; int i2 = cc - q*3;
                    int srcl = (l & 48) | q;
                    float g0 = __shfl(a0, srcl), g1 = __shfl(a1, srcl), g2 = __shfl(a2, srcl);
                    float oo = (i2==0) ? g0 : ((i2==1) ? g1 : g2);
                    float xq = __shfl(xc, srcl);
                    if (cc < 12) {
                        float sh1i = sSh[el*3 + i2];
                        tp[(rowbase + el)*40 + 16 + cc] = A0 * (xq * sh1i + oo);
                    }
                }
            } else {                          // we: cross(v, sh1), store cols 28..39
                int base3 = (cc >> 2) * 3;
                #pragma unroll
                for (int r = 0; r < 4; ++r) {
                    int el = elb + r;
                    float vx = sV[(base3+0)*260 + el];
                    float vy = sV[(base3+1)*260 + el];
                    float vz = sV[(base3+2)*260 + el];
                    float sx = sSh[el*3+0], sy = sSh[el*3+1], sz = sSh[el*3+2];
                    float cx = vy*sz - vz*sy;
                    float cy = vz*sx - vx*sz;
                    float cz = vx*sy - vy*sx;
                    float a0 = D[r]*cx, a1 = D[r]*cy, a2 = D[r]*cz;
                    a0 += __shfl_xor(a0,4); a0 += __shfl_xor(a0,8);
                    a1 += __shfl_xor(a1,4); a1 += __shfl_xor(a1,8);
                    a2 += __shfl_xor(a2,4); a2 += __shfl_xor(a2,8);
                    int q = cc / 3; int i2 = cc - q*3;
                    int srcl = (l & 48) | q;
                    float g0 = __shfl(a0, srcl), g1 = __shfl(a1, srcl), g2 = __shfl(a2, srcl);
                    float oo = (i2==0) ? g0 : ((i2==1) ? g1 : g2);
                    if (cc < 12)
                        tp[(rowbase + el)*40 + 28 + cc] = AE * oo;
                }
            }
        }
    };

    B4 b0 = loadB(gB, 0, l), b1v = loadB(gB, 1, l);
    #pragma unroll 1
    for (int t = 0; t < 26; t += 2) {
        B4 p0 = (t + 2 < 26) ? loadB(gB, t + 2, l) : b0;
        process(t, b0);
        B4 p1 = (t + 3 < 26) ? loadB(gB, t + 3, l) : b1v;
        process(t + 1, b1v);
        b0 = p0; b1v = p1;
    }

    // out0 stores (cols 0..15)
    #pragma unroll
    for (int mt = 0; mt < 4; ++mt) {
        int elb = (tid & 192) + (mt << 4) + ((l >> 4) << 2);
        #pragma unroll
        for (int r = 0; r < 4; ++r) {
            int el = elb + r;
            tp[(rowbase + el)*40 + cc] = out0[mt][r] * A0;
        }
    }
}

// segment mean over sorted edge rows: out[n*C+c] = mean(tp[rowptr[n]..rowptr[n+1]][c])
template<int C>
__global__ __launch_bounds__(256)
void k_gather(const float* __restrict__ tp, const int* __restrict__ rowptr,
              float* __restrict__ out)
{
    int i = blockIdx.x*256 + threadIdx.x;
    if (i >= NN*C) return;
    int n = i / C; int c = i - n*C;
    int r0 = rowptr[n], r1 = rowptr[n+1];
    float s0=0.f, s1=0.f, s2=0.f, s3=0.f;
    int r = r0;
    for (; r + 4 <= r1; r += 4) {
        s0 += tp[(size_t)(r+0)*C + c];
        s1 += tp[(size_t)(r+1)*C + c];
        s2 += tp[(size_t)(r+2)*C + c];
        s3 += tp[(size_t)(r+3)*C + c];
    }
    for (; r < r1; ++r) s0 += tp[(size_t)r*C + c];
    float sum = (s0 + s1) + (s2 + s3);
    float inv = (r1 > r0) ? 1.0f / (float)(r1 - r0) : 1.0f;
    out[i] = sum * inv;
}

extern "C" void kernel_launch(void* const* d_in, const int* in_sizes, int n_in,
                              void* d_out, int out_size, void* d_ws, size_t ws_size,
                              hipStream_t stream) {
    const int*   x_cat     = (const int*)  d_in[0];
    const float* x_scalar  = (const float*)d_in[1];
    const float* pos       = (const float*)d_in[2];
    const int*   ei        = (const int*)  d_in[3];
    const float* edge_bond = (const float*)d_in[4];
    const float* emb       = (const float*)d_in[5];
    const float* node_w    = (const float*)d_in[6];
    const float* node_b    = (const float*)d_in[7];
    const float* em_w1     = (const float*)d_in[8];
    const float* em_b1     = (const float*)d_in[9];
    const float* em_w2     = (const float*)d_in[10];
    const float* em_b2     = (const float*)d_in[11];
    const float* c1_w1     = (const float*)d_in[12];
    const float* c1_b1     = (const float*)d_in[13];
    const float* c1_w2     = (const float*)d_in[14];
    const float* c1_b2     = (const float*)d_in[15];
    const float* c2_w1     = (const float*)d_in[16];
    const float* c2_b1     = (const float*)d_in[17];
    const float* c2_w2     = (const float*)d_in[18];
    const float* c2_b2     = (const float*)d_in[19];

    float* ws    = (float*)d_ws;
    float* node0 = ws;                              // 320,000
    float* node1 = ws + 320000;                     // 560,000
    int*   degI  = (int*)(ws + 880000);             // 20,000
    int*   rowp  = (int*)(ws + 900000);             // 20,008
    int*   offI  = (int*)(ws + 920008);             // 20,000
    int*   permI = (int*)(ws + 940008);             // 320,000
    ushort_t* packA = (ushort_t*)(ws + 1260008);    // 20*2048 ushorts
    ushort_t* packB = packA + 20*2048;              // 26*2048 ushorts (ends 1,307,112)
    float* eembG = ws + 1307112;                    // NE*16 = 5,120,000
    float* eshG  = ws + 6427112;                    // NE*4  = 1,280,000
    float* yBuf  = ws + 7707112;                    // NN*96 = 1,920,000
    float* tp    = ws + 9627112;                    // NE*40 = 12,800,000 (ends 22,427,112 = 89.7 MB)

    hipMemsetAsync(degI, 0, 20000 * sizeof(int), stream);

    k_deg<<<(NE + 255) / 256, 256, 0, stream>>>(ei, degI);
    k_scan<<<1, 256, 0, stream>>>(degI, rowp, offI);
    k_scatter<<<(NE + 255) / 256, 256, 0, stream>>>(ei, offI, permI);

    k_pack<<<(20*128 + 255) / 256, 256, 0, stream>>>(c1_w2, c1_b2, packA, 320, 20);
    k_pack<<<(26*128 + 255) / 256, 256, 0, stream>>>(c2_w2, c2_b2, packB, 416, 26);

    k_node_feat<<<(NN + 255) / 256, 256, 0, stream>>>(
        x_cat, x_scalar, emb, node_w, node_b, node0);

    k_node_y<<<(NN + 255) / 256, 256, 0, stream>>>(node0, 16, c1_w1, yBuf);

    k_edge_l1<<<NE / 256, 256, 0, stream>>>(
        ei, pos, edge_bond, em_w1, em_b1, em_w2, em_b2,
        c1_w1, c1_b1, packA, yBuf, node0, permI, eembG, eshG, tp);

    k_gather<28><<<(NN*28 + 255) / 256, 256, 0, stream>>>(tp, rowp, node1);

    k_node_y<<<(NN + 255) / 256, 256, 0, stream>>>(node1, 28, c2_w1, yBuf);

    k_edge_l2<<<NE / 256, 256, 0, stream>>>(
        ei, c2_w1, c2_b1, packB, eembG, eshG, yBuf, node1, permI, tp);

    k_gather<40><<<(NN*40 + 255) / 256, 256, 0, stream>>>(tp, rowp, (float*)d_out);
}

// Round 11
// 329.279 us; speedup vs baseline: 1.2886x; 1.2886x over previous
//
#include <hip/hip_runtime.h>
#include <math.h>

#define NN 20000
#define NE 320000

typedef _Float16 f16x8 __attribute__((ext_vector_type(8)));
typedef float f32x4 __attribute__((ext_vector_type(4)));
typedef unsigned short ushort_t;
typedef unsigned int uint_t;

#define MFMA16(A,B,C) __builtin_amdgcn_mfma_f32_16x16x32_f16((A),(B),(C),0,0,0)
#define LDS_FENCE() do{ asm volatile("s_waitcnt lgkmcnt(0)" ::: "memory"); __builtin_amdgcn_sched_barrier(0);}while(0)

static_assert(NE % 64 == 0, "edge grid must tile exactly");

__device__ __forceinline__ float frelu(float x){ return fmaxf(x, 0.0f); }

// split x = hi + lo * 2^-11  (lo stored pre-scaled by 2^11 to stay f16-normal)
__device__ __forceinline__ void splitf(float x, ushort_t& h, ushort_t& l){
    _Float16 hh = (_Float16)x;
    float r = (x - (float)hh) * 2048.0f;
    _Float16 ll = (_Float16)r;
    union { _Float16 f; ushort_t u; } ch, cl;
    ch.f = hh; cl.f = ll;
    h = ch.u; l = cl.u;
}

__device__ __forceinline__ void edge_embed(
    int e, int s, int d,
    const float* __restrict__ pos,
    const float* __restrict__ edge_bond,
    const float* __restrict__ em_w1, const float* __restrict__ em_b1,
    const float* __restrict__ em_w2, const float* __restrict__ em_b2,
    float* eemb, float* sh1)
{
    float vx = pos[d*3+0] - pos[s*3+0];
    float vy = pos[d*3+1] - pos[s*3+1];
    float vz = pos[d*3+2] - pos[s*3+2];
    float d2 = vx*vx + vy*vy + vz*vz + 1e-12f;
    float dist = sqrtf(d2);
    float inv = 1.0f / (dist + 1e-8f);
    const float SQ3 = 1.7320508075688772f;
    sh1[0] = SQ3 * vx * inv;
    sh1[1] = SQ3 * vy * inv;
    sh1[2] = SQ3 * vz * inv;

    float ein[42];
    #pragma unroll
    for (int t = 0; t < 10; ++t) ein[t] = edge_bond[e*10 + t];
    const float coeff = -19.22f;            // -0.5 / (5/31)^2
    const float step  = 5.0f / 31.0f;
    #pragma unroll
    for (int k = 0; k < 32; ++k) {
        float dd = dist - step * (float)k;
        ein[10+k] = __expf(coeff * dd * dd);
    }

    float t1[16];
    #pragma unroll
    for (int j = 0; j < 16; ++j) t1[j] = em_b1[j];
    #pragma unroll
    for (int t = 0; t < 42; ++t) {
        float v = ein[t];
        #pragma unroll
        for (int j = 0; j < 16; ++j) t1[j] += v * em_w1[t*16 + j];
    }
    #pragma unroll
    for (int j = 0; j < 16; ++j) t1[j] = frelu(t1[j]);

    #pragma unroll
    for (int j = 0; j < 16; ++j) eemb[j] = em_b2[j];
    #pragma unroll
    for (int t = 0; t < 16; ++t) {
        float v = t1[t];
        #pragma unroll
        for (int j = 0; j < 16; ++j) eemb[j] += v * em_w2[t*16 + j];
    }
}

// ---- per-node W1 partials: yB = node@W1[16:32], yC = node@W1[32:48] ----
__global__ __launch_bounds__(256)
void k_node_y(const float* __restrict__ node, int stride,
              const float* __restrict__ w1, float* __restrict__ y)
{
    int n = blockIdx.x*256 + threadIdx.x;
    if (n >= NN) return;
    float sv[16];
    const float4* r = reinterpret_cast<const float4*>(node + (size_t)n*stride);
    #pragma unroll
    for (int k = 0; k < 4; ++k) {
        float4 q = r[k];
        sv[4*k]=q.x; sv[4*k+1]=q.y; sv[4*k+2]=q.z; sv[4*k+3]=q.w;
    }
    float yb[48];
    #pragma unroll
    for (int j = 0; j < 48; ++j) yb[j] = 0.f;
    #pragma unroll
    for (int t = 0; t < 16; ++t) {
        float v = sv[t];
        #pragma unroll
        for (int j = 0; j < 48; ++j) yb[j] += v * w1[(16+t)*48 + j];
    }
    float* yo = y + (size_t)n*96;
    #pragma unroll
    for (int j = 0; j < 12; ++j)
        reinterpret_cast<float4*>(yo)[j] = make_float4(yb[4*j], yb[4*j+1], yb[4*j+2], yb[4*j+3]);
    #pragma unroll
    for (int j = 0; j < 48; ++j) yb[j] = 0.f;
    #pragma unroll
    for (int t = 0; t < 16; ++t) {
        float v = sv[t];
        #pragma unroll
        for (int j = 0; j < 48; ++j) yb[j] += v * w1[(32+t)*48 + j];
    }
    #pragma unroll
    for (int j = 0; j < 12; ++j)
        reinterpret_cast<float4*>(yo + 48)[j] = make_float4(yb[4*j], yb[4*j+1], yb[4*j+2], yb[4*j+3]);
}

// One-time pack of W2' (K=49 rows incl bias, zero-pad to 64) into global hi/lo
__global__ __launch_bounds__(256)
void k_pack(const float* __restrict__ w2, const float* __restrict__ b2,
            ushort_t* __restrict__ out, int NC, int ntiles)
{
    int slot = blockIdx.x*256 + threadIdx.x;
    if (slot >= ntiles*128) return;
    int tl = slot >> 7; int r7 = slot & 127; int kb = r7 >> 6; int ll = r7 & 63;
    int col = tl*16 + (ll & 15);
    int k0 = (kb<<5) + ((ll>>4)<<3);
    uint_t hw[4], lw[4];
    #pragma unroll
    for (int p = 0; p < 4; ++p) {
        int ka = k0 + 2*p, kb2 = k0 + 2*p + 1;
        float va = (ka < 48) ? w2[ka*NC + col] : (ka == 48 ? b2[col] : 0.0f);
        float vb = (kb2 < 48) ? w2[kb2*NC + col] : (kb2 == 48 ? b2[col] : 0.0f);
        ushort_t ah, al, bh, bl;
        splitf(va, ah, al);
        splitf(vb, bh, bl);
        hw[p] = (uint_t)ah | ((uint_t)bh << 16);
        lw[p] = (uint_t)al | ((uint_t)bl << 16);
    }
    int base = tl*2048 + kb*1024 + ll*8;
    *reinterpret_cast<uint4*>(&out[base])       = make_uint4(hw[0], hw[1], hw[2], hw[3]);
    *reinterpret_cast<uint4*>(&out[base + 512]) = make_uint4(lw[0], lw[1], lw[2], lw[3]);
}

struct B4 { f16x8 h0, l0, h1, l1; };
__device__ __forceinline__ B4 loadB(const f16x8* __restrict__ g, int t, int l) {
    B4 b;
    const f16x8* p = g + t*256 + l;
    b.h0 = p[0];
    b.l0 = p[64];
    b.h1 = p[128];
    b.l1 = p[192];
    return b;
}

// Per-wave A-frag staging through a 4 KB bounce (hi+lo in one pass, 2 fences/mt).
__device__ __forceinline__ void stage_A(ushort_t* bounce, int l,
                                        const uint_t* hph, const uint_t* hpl,
                                        f16x8 ahi[4][2], f16x8 alo[4][2])
{
    #pragma unroll
    for (int t = 0; t < 4; ++t)
        *reinterpret_cast<uint4*>(&bounce[l*32 + t*8]) = make_uint4(0,0,0,0);
    LDS_FENCE();
    #pragma unroll
    for (int mt = 0; mt < 4; ++mt) {
        if ((l >> 4) == mt) {
            #pragma unroll
            for (int jj = 0; jj < 25; ++jj) {
                int k = jj*2, kb = k >> 5, kk = k & 31;
                int lr = (l & 15) + ((kk >> 3) << 4);
                int off = kb*512 + lr*8 + (kk & 7);
                *reinterpret_cast<uint_t*>(&bounce[off])        = hph[jj];
                *reinterpret_cast<uint_t*>(&bounce[1024 + off]) = hpl[jj];
            }
        }
        LDS_FENCE();
        ahi[mt][0] = *reinterpret_cast<const f16x8*>(&bounce[l*8]);
        ahi[mt][1] = *reinterpret_cast<const f16x8*>(&bounce[512 + l*8]);
        alo[mt][0] = *reinterpret_cast<const f16x8*>(&bounce[1024 + l*8]);
        alo[mt][1] = *reinterpret_cast<const f16x8*>(&bounce[1536 + l*8]);
        LDS_FENCE();
    }
}

// h = relu(b1 + em@W1[0:16] + yB[s] + yC[d]), em already in registers
__device__ __forceinline__ void build_h_reg(
    const float* em, int s, int d,
    const float* __restrict__ y,
    const float* __restrict__ w1, const float* __restrict__ b1,
    float* h)
{
    #pragma unroll
    for (int j = 0; j < 48; ++j) h[j] = b1[j];
    #pragma unroll
    for (int t = 0; t < 16; ++t) {
        float v = em[t];
        #pragma unroll
        for (int j = 0; j < 48; ++j) h[j] += v * w1[t*48 + j];
    }
    const float4* pb = reinterpret_cast<const float4*>(y + (size_t)s*96);
    const float4* pc = reinterpret_cast<const float4*>(y + (size_t)d*96 + 48);
    #pragma unroll
    for (int kk = 0; kk < 12; ++kk) {
        float4 qb = pb[kk], qc = pc[kk];
        h[4*kk+0] = frelu(h[4*kk+0] + qb.x + qc.x);
        h[4*kk+1] = frelu(h[4*kk+1] + qb.y + qc.y);
        h[4*kk+2] = frelu(h[4*kk+2] + qb.z + qc.z);
        h[4*kk+3] = frelu(h[4*kk+3] + qb.w + qc.w);
    }
}

__global__ __launch_bounds__(256)
void k_node_feat(const int* __restrict__ x_cat, const float* __restrict__ x_scalar,
                 const float* __restrict__ emb, const float* __restrict__ node_w,
                 const float* __restrict__ node_b, float* __restrict__ node0)
{
    int n = blockIdx.x * 256 + threadIdx.x;
    if (n >= NN) return;
    float acc[16];
    #pragma unroll
    for (int k = 0; k < 16; ++k) acc[k] = node_b[k];
    #pragma unroll
    for (int c = 0; c < 10; ++c) {
        int idx = x_cat[n*10 + c];
        const float4* row = reinterpret_cast<const float4*>(emb + (c*119 + idx)*16);
        #pragma unroll
        for (int k = 0; k < 4; ++k) {
            float4 q = row[k];
            acc[4*k+0] += q.x; acc[4*k+1] += q.y; acc[4*k+2] += q.z; acc[4*k+3] += q.w;
        }
    }
    #pragma unroll
    for (int t = 0; t < 32; ++t) {
        float xs = x_scalar[n*32 + t];
        #pragma unroll
        for (int k = 0; k < 16; ++k) acc[k] += xs * node_w[t*16 + k];
    }
    #pragma unroll
    for (int k = 0; k < 16; ++k) node0[n*16 + k] = acc[k];
}

// ---------------- Layer 1: single-wave blocks, 64 edges each ----------------
__global__ __launch_bounds__(64)
void k_edge_l1(const int* __restrict__ ei, const float* __restrict__ pos,
               const float* __restrict__ edge_bond,
               const float* __restrict__ em_w1, const float* __restrict__ em_b1,
               const float* __restrict__ em_w2, const float* __restrict__ em_b2,
               const float* __restrict__ w1, const float* __restrict__ b1,
               const ushort_t* __restrict__ packW,
               const float* __restrict__ y,
               const float* __restrict__ node0,
               float* __restrict__ eembG, float* __restrict__ eshG,
               float* __restrict__ accum, float* __restrict__ cnt)
{
    // union: bounce(4096B) overlays sT; sT filled after stage_A
    __shared__ __align__(16) unsigned char smem[5376];
    float* sT  = (float*)smem;                    // 16*68*4 = 4352
    float* sSh = (float*)(smem + 4352);           // 768
    int*   sSrc= (int*)(smem + 5120);             // 256

    int l = threadIdx.x;          // 0..63
    int cc = l & 15;
    int e = blockIdx.x*64 + l;
    int s = ei[e], d = ei[NE + e];

    float em[16], sh1[3];
    edge_embed(e, s, d, pos, edge_bond, em_w1, em_b1, em_w2, em_b2, em, sh1);
    {
        float4* pe = reinterpret_cast<float4*>(eembG + (size_t)e*16);
        #pragma unroll
        for (int k = 0; k < 4; ++k)
            pe[k] = make_float4(em[4*k], em[4*k+1], em[4*k+2], em[4*k+3]);
        reinterpret_cast<float4*>(eshG)[e] = make_float4(sh1[0], sh1[1], sh1[2], 0.f);
    }
    atomicAdd(cnt + s, 1.0f);

    float sd[16];
    {
        const float4* rd = reinterpret_cast<const float4*>(node0 + (size_t)d*16);
        #pragma unroll
        for (int k = 0; k < 4; ++k) {
            float4 q = rd[k];
            sd[4*k]=q.x; sd[4*k+1]=q.y; sd[4*k+2]=q.z; sd[4*k+3]=q.w;
        }
    }
    float h[48];
    build_h_reg(em, s, d, y, w1, b1, h);

    uint_t hph[25], hpl[25];
    #pragma unroll
    for (int jj = 0; jj < 24; ++jj) {
        ushort_t ah, al, bh, bl;
        splitf(h[2*jj],   ah, al);
        splitf(h[2*jj+1], bh, bl);
        hph[jj] = (uint_t)ah | ((uint_t)bh << 16);
        hpl[jj] = (uint_t)al | ((uint_t)bl << 16);
    }
    hph[24] = 0x3C00u;  // k=48 -> 1.0 (bias feature), k=49 -> 0
    hpl[24] = 0u;

    f16x8 ahi[4][2], alo[4][2];
    stage_A((ushort_t*)smem, l, hph, hpl, ahi, alo);

    LDS_FENCE();                 // bounce reads done; reuse region for sT
    sSrc[l] = s;
    #pragma unroll
    for (int u = 0; u < 16; ++u) sT[u*68 + l] = sd[u];
    sSh[l*3+0] = sh1[0]; sSh[l*3+1] = sh1[1]; sSh[l*3+2] = sh1[2];
    LDS_FENCE();                 // cross-lane visibility before reads

    f32x4 out0[4];
    float ob[4][4];
    #pragma unroll
    for (int mt = 0; mt < 4; ++mt) {
        out0[mt] = (f32x4){0.f,0.f,0.f,0.f};
        #pragma unroll
        for (int r = 0; r < 4; ++r) ob[mt][r] = 0.f;
    }

    const f16x8* gB = reinterpret_cast<const f16x8*>(packW);

    auto process = [&](int t, const B4& cur) {
        #pragma unroll
        for (int mt = 0; mt < 4; ++mt) {
            f32x4 Dh = (f32x4){0.f,0.f,0.f,0.f};
            f32x4 Dc = (f32x4){0.f,0.f,0.f,0.f};
            Dh = MFMA16(ahi[mt][0], cur.h0, Dh);
            Dh = MFMA16(ahi[mt][1], cur.h1, Dh);
            Dc = MFMA16(alo[mt][0], cur.h0, Dc);
            Dc = MFMA16(ahi[mt][0], cur.l0, Dc);
            Dc = MFMA16(alo[mt][1], cur.h1, Dc);
            Dc = MFMA16(ahi[mt][1], cur.l1, Dc);
            f32x4 D = Dh + Dc * 0.00048828125f;   // 2^-11
            int elb = (mt << 4) + ((l >> 4) << 2);
            if (t < 16) {
                f32x4 sv = *reinterpret_cast<const f32x4*>(&sT[t*68 + elb]);
                out0[mt] += sv * D;
            } else {
                const float* sp = &sT[(((t-16)<<2) + (cc>>2))*68 + elb];
                #pragma unroll
                for (int r = 0; r < 4; ++r) ob[mt][r] += sp[r] * D[r];
            }
        }
    };

    B4 b0 = loadB(gB, 0, l), b1v = loadB(gB, 1, l);
    #pragma unroll 1
    for (int t = 0; t < 20; t += 2) {
        B4 p0 = (t + 2 < 20) ? loadB(gB, t + 2, l) : b0;
        process(t, b0);
        B4 p1 = (t + 3 < 20) ? loadB(gB, t + 3, l) : b1v;
        process(t + 1, b1v);
        b0 = p0; b1v = p1;
    }

    // epilogue
    #pragma unroll
    for (int mt = 0; mt < 4; ++mt) {
        int elb = (mt << 4) + ((l >> 4) << 2);
        #pragma unroll
        for (int r = 0; r < 4; ++r) {
            int el = elb + r;
            int sidx = sSrc[el];
            atomicAdd(accum + (size_t)sidx*28 + cc, out0[mt][r] * 0.25f);
            float x = ob[mt][r];
            x += __shfl_xor(x, 4); x += __shfl_xor(x, 8);
            int q = cc / 3; int i2 = cc - q*3;
            float xq = __shfl(x, (l & 48) | q);
            if (cc < 12)
                atomicAdd(accum + (size_t)sidx*28 + 16 + cc, 0.25f * xq * sSh[el*3 + i2]);
        }
    }
}

// ---------------- Layer 2: single-wave blocks, 64 edges each ----------------
__global__ __launch_bounds__(64)
void k_edge_l2(const int* __restrict__ ei,
               const float* __restrict__ w1, const float* __restrict__ b1,
               const ushort_t* __restrict__ packW,
               const float* __restrict__ eembG, const float* __restrict__ eshG,
               const float* __restrict__ y,
               const float* __restrict__ node1,
               float* __restrict__ accum2)
{
    __shared__ __align__(16) unsigned char smem[9728];
    float* sT  = (float*)smem;                    // 16*68*4 = 4352 (bounce union)
    float* sVd = (float*)(smem + 4352);           // 4*68*4 = 1088
    float* sV  = (float*)(smem + 5440);           // 12*68*4 = 3264
    float* sSh = (float*)(smem + 8704);           // 768
    int*   sSrc= (int*)(smem + 9472);             // 256

    int l = threadIdx.x;
    int cc = l & 15;
    int e = blockIdx.x*64 + l;
    int s = ei[e], d = ei[NE + e];

    float4 shv = reinterpret_cast<const float4*>(eshG)[e];
    float sh1[3] = {shv.x, shv.y, shv.z};
    float sd[16], vv[12];
    {
        const float4* rd = reinterpret_cast<const float4*>(node1 + (size_t)d*28);
        #pragma unroll
        for (int k = 0; k < 4; ++k) {
            float4 q = rd[k];
            sd[4*k]=q.x; sd[4*k+1]=q.y; sd[4*k+2]=q.z; sd[4*k+3]=q.w;
        }
        #pragma unroll
        for (int k = 0; k < 3; ++k) {
            float4 q = rd[4+k];
            vv[4*k]=q.x; vv[4*k+1]=q.y; vv[4*k+2]=q.z; vv[4*k+3]=q.w;
        }
    }
    float vdr[4];
    const float INV_SQ3 = 0.5773502691896258f;
    #pragma unroll
    for (int u = 0; u < 4; ++u)
        vdr[u] = (vv[u*3]*sh1[0] + vv[u*3+1]*sh1[1] + vv[u*3+2]*sh1[2]) * INV_SQ3;

    float em[16];
    {
        const float4* pe = reinterpret_cast<const float4*>(eembG + (size_t)e*16);
        #pragma unroll
        for (int k = 0; k < 4; ++k) {
            float4 q = pe[k];
            em[4*k]=q.x; em[4*k+1]=q.y; em[4*k+2]=q.z; em[4*k+3]=q.w;
        }
    }
    float h[48];
    build_h_reg(em, s, d, y, w1, b1, h);

    uint_t hph[25], hpl[25];
    #pragma unroll
    for (int jj = 0; jj < 24; ++jj) {
        ushort_t ah, al, bh, bl;
        splitf(h[2*jj],   ah, al);
        splitf(h[2*jj+1], bh, bl);
        hph[jj] = (uint_t)ah | ((uint_t)bh << 16);
        hpl[jj] = (uint_t)al | ((uint_t)bl << 16);
    }
    hph[24] = 0x3C00u;
    hpl[24] = 0u;

    f16x8 ahi[4][2], alo[4][2];
    stage_A((ushort_t*)smem, l, hph, hpl, ahi, alo);

    LDS_FENCE();
    sSrc[l] = s;
    #pragma unroll
    for (int u = 0; u < 16; ++u) sT[u*68 + l] = sd[u];
    #pragma unroll
    for (int u = 0; u < 4; ++u) sVd[u*68 + l] = vdr[u];
    #pragma unroll
    for (int k = 0; k < 12; ++k) sV[k*68 + l] = vv[k];
    sSh[l*3+0] = sh1[0]; sSh[l*3+1] = sh1[1]; sSh[l*3+2] = sh1[2];
    LDS_FENCE();

    const float A0 = 0.22360679774997896f;   // 1/sqrt(20)
    const float AE = 0.3535533905932738f;    // 0.5/sqrt(2)

    f32x4 out0[4];
    float outc[4][4];
    #pragma unroll
    for (int mt = 0; mt < 4; ++mt) {
        out0[mt] = (f32x4){0.f,0.f,0.f,0.f};
        #pragma unroll
        for (int r = 0; r < 4; ++r) outc[mt][r] = 0.f;
    }

    const f16x8* gB = reinterpret_cast<const f16x8*>(packW);

    auto process = [&](int t, const B4& cur) {
        #pragma unroll
        for (int mt = 0; mt < 4; ++mt) {
            f32x4 Dh = (f32x4){0.f,0.f,0.f,0.f};
            f32x4 Dc = (f32x4){0.f,0.f,0.f,0.f};
            Dh = MFMA16(ahi[mt][0], cur.h0, Dh);
            Dh = MFMA16(ahi[mt][1], cur.h1, Dh);
            Dc = MFMA16(alo[mt][0], cur.h0, Dc);
            Dc = MFMA16(ahi[mt][0], cur.l0, Dc);
            Dc = MFMA16(alo[mt][1], cur.h1, Dc);
            Dc = MFMA16(ahi[mt][1], cur.l1, Dc);
            f32x4 D = Dh + Dc * 0.00048828125f;
            int elb = (mt << 4) + ((l >> 4) << 2);
            if (t < 16) {                     // wa: contract s
                f32x4 sv = *reinterpret_cast<const f32x4*>(&sT[t*68 + elb]);
                out0[mt] += sv * D;
            } else if (t < 20) {              // wb: contract vdot/sqrt3
                f32x4 vd = *reinterpret_cast<const f32x4*>(&sVd[(t-16)*68 + elb]);
                out0[mt] += vd * D;
            } else if (t < 24) {              // wc: contract s -> outc[q]
                const float* sp = &sT[(((t-20)<<2) + (cc>>2))*68 + elb];
                #pragma unroll
                for (int r = 0; r < 4; ++r) outc[mt][r] += sp[r] * D[r];
            } else if (t == 24) {             // wd: + combined scatter of cols 16..27
                int base3 = (cc >> 2) * 3;
                #pragma unroll
                for (int r = 0; r < 4; ++r) {
                    int el = elb + r;
                    float vx = sV[(base3+0)*68 + el];
                    float vy = sV[(base3+1)*68 + el];
                    float vz = sV[(base3+2)*68 + el];
                    float a0 = D[r]*vx, a1 = D[r]*vy, a2 = D[r]*vz;
                    a0 += __shfl_xor(a0,4); a0 += __shfl_xor(a0,8);
                    a1 += __shfl_xor(a1,4); a1 += __shfl_xor(a1,8);
                    a2 += __shfl_xor(a2,4); a2 += __shfl_xor(a2,8);
                    float xc = outc[mt][r];
                    xc += __shfl_xor(xc,4); xc += __shfl_xor(xc,8);
                    int q = cc / 3; int i2 = cc - q*3;
                    int srcl = (l & 48) | q;
                    float g0 = __shfl(a0, srcl), g1 = __shfl(a1, srcl), g2 = __shfl(a2, srcl);
                    float oo = (i2==0) ? g0 : ((i2==1) ? g1 : g2);
                    float xq = __shfl(xc, srcl);
                    if (cc < 12) {
                        float sh1i = sSh[el*3 + i2];
                        atomicAdd(accum2 + (size_t)sSrc[el]*40 + 16 + cc,
                                  A0 * (xq * sh1i + oo));
                    }
                }
            } else {                          // we: cross(v, sh1), cols 28..39
                int base3 = (cc >> 2) * 3;
                #pragma unroll
                for (int r = 0; r < 4; ++r) {
                    int el = elb + r;
                    float vx = sV[(base3+0)*68 + el];
                    float vy = sV[(base3+1)*68 + el];
                    float vz = sV[(base3+2)*68 + el];
                    float sx = sSh[el*3+0], sy = sSh[el*3+1], sz = sSh[el*3+2];
                    float cx = vy*sz - vz*sy;
                    float cy = vz*sx - vx*sz;
                    float cz = vx*sy - vy*sx;
                    float a0 = D[r]*cx, a1 = D[r]*cy, a2 = D[r]*cz;
                    a0 += __shfl_xor(a0,4); a0 += __shfl_xor(a0,8);
                    a1 += __shfl_xor(a1,4); a1 += __shfl_xor(a1,8);
                    a2 += __shfl_xor(a2,4); a2 += __shfl_xor(a2,8);
                    int q = cc / 3; int i2 = cc - q*3;
                    int srcl = (l & 48) | q;
                    float g0 = __shfl(a0, srcl), g1 = __shfl(a1, srcl), g2 = __shfl(a2, srcl);
                    float oo = (i2==0) ? g0 : ((i2==1) ? g1 : g2);
                    if (cc < 12)
                        atomicAdd(accum2 + (size_t)sSrc[el]*40 + 28 + cc, AE * oo);
                }
            }
        }
    };

    B4 b0 = loadB(gB, 0, l), b1v = loadB(gB, 1, l);
    #pragma unroll 1
    for (int t = 0; t < 26; t += 2) {
        B4 p0 = (t + 2 < 26) ? loadB(gB, t + 2, l) : b0;
        process(t, b0);
        B4 p1 = (t + 3 < 26) ? loadB(gB, t + 3, l) : b1v;
        process(t + 1, b1v);
        b0 = p0; b1v = p1;
    }

    // out0 scatter (cols 0..15)
    #pragma unroll
    for (int mt = 0; mt < 4; ++mt) {
        int elb = (mt << 4) + ((l >> 4) << 2);
        #pragma unroll
        for (int r = 0; r < 4; ++r) {
            int el = elb + r;
            atomicAdd(accum2 + (size_t)sSrc[el]*40 + cc, out0[mt][r] * A0);
        }
    }
}

__global__ __launch_bounds__(256)
void k_div(const float* __restrict__ in, float* __restrict__ out,
           const float* __restrict__ cnt, int cols, int total)
{
    int i = blockIdx.x * 256 + threadIdx.x;
    if (i >= total) return;
    int n = i / cols;
    out[i] = in[i] / fmaxf(cnt[n], 1.0f);
}

extern "C" void kernel_launch(void* const* d_in, const int* in_sizes, int n_in,
                              void* d_out, int out_size, void* d_ws, size_t ws_size,
                              hipStream_t stream) {
    const int*   x_cat     = (const int*)  d_in[0];
    const float* x_scalar  = (const float*)d_in[1];
    const float* pos       = (const float*)d_in[2];
    const int*   ei        = (const int*)  d_in[3];
    const float* edge_bond = (const float*)d_in[4];
    const float* emb       = (const float*)d_in[5];
    const float* node_w    = (const float*)d_in[6];
    const float* node_b    = (const float*)d_in[7];
    const float* em_w1     = (const float*)d_in[8];
    const float* em_b1     = (const float*)d_in[9];
    const float* em_w2     = (const float*)d_in[10];
    const float* em_b2     = (const float*)d_in[11];
    const float* c1_w1     = (const float*)d_in[12];
    const float* c1_b1     = (const float*)d_in[13];
    const float* c1_w2     = (const float*)d_in[14];
    const float* c1_b2     = (const float*)d_in[15];
    const float* c2_w1     = (const float*)d_in[16];
    const float* c2_b1     = (const float*)d_in[17];
    const float* c2_w2     = (const float*)d_in[18];
    const float* c2_b2     = (const float*)d_in[19];

    float* ws    = (float*)d_ws;
    float* node0 = ws;                              // 320,000
    float* accum1= ws + 320000;                     // 560,000
    float* accum2= ws + 880000;                     // 800,000
    float* cnt   = ws + 1680000;                    // 20,000
    float* node1 = ws + 1700000;                    // 560,000
    ushort_t* packA = (ushort_t*)(ws + 2260000);    // 20*2048 ushorts
    ushort_t* packB = packA + 20*2048;              // 26*2048 ushorts (ends 2,307,104)
    float* eembG = ws + 2307104;                    // NE*16 = 5,120,000
    float* eshG  = ws + 7427104;                    // NE*4  = 1,280,000
    float* yBuf  = ws + 8707104;                    // NN*96 = 1,920,000  (total ~42.5 MB)

    hipMemsetAsync(accum1, 0, (size_t)(560000 + 800000 + 20000) * sizeof(float), stream);

    k_pack<<<(20*128 + 255) / 256, 256, 0, stream>>>(c1_w2, c1_b2, packA, 320, 20);
    k_pack<<<(26*128 + 255) / 256, 256, 0, stream>>>(c2_w2, c2_b2, packB, 416, 26);

    k_node_feat<<<(NN + 255) / 256, 256, 0, stream>>>(
        x_cat, x_scalar, emb, node_w, node_b, node0);

    k_node_y<<<(NN + 255) / 256, 256, 0, stream>>>(node0, 16, c1_w1, yBuf);

    k_edge_l1<<<NE / 64, 64, 0, stream>>>(
        ei, pos, edge_bond, em_w1, em_b1, em_w2, em_b2,
        c1_w1, c1_b1, packA, yBuf, node0, eembG, eshG, accum1, cnt);

    k_div<<<(560000 + 255) / 256, 256, 0, stream>>>(accum1, node1, cnt, 28, 560000);

    k_node_y<<<(NN + 255) / 256, 256, 0, stream>>>(node1, 28, c2_w1, yBuf);

    k_edge_l2<<<NE / 64, 64, 0, stream>>>(
        ei, c2_w1, c2_b1, packB, eembG, eshG, yBuf, node1, accum2);

    k_div<<<(800000 + 255) / 256, 256, 0, stream>>>(accum2, (float*)d_out, cnt, 40, 800000);
}